// Round 5
// baseline (222.135 us; speedup 1.0000x reference)
//
#include <hip/hip_runtime.h>

constexpr int Bn = 8, Cn = 3, Hn = 720, Wn = 1280;
constexpr int HW = Hn * Wn;                    // 921600 px per image
constexpr long long NTOT = (long long)Bn * Cn * HW;

constexpr int BLK   = 256;
constexpr int NBX   = 360;                     // blocks per XCD (= per batch)
constexpr int NWG   = 8 * NBX;                 // 2880 blocks
constexpr int PX    = 2;                       // pixel-chunks per thread per iter
constexpr int ITER2 = HW / (NBX * BLK * PX);   // 5 iterations, exact

__device__ __forceinline__ void mk_coords(float xf, float yf,
                                          int& i00, int& i01, int& i10, int& i11,
                                          float& wx, float& wy) {
    xf = fminf(fmaxf(xf, 0.f), (float)(Wn - 1));
    yf = fminf(fmaxf(yf, 0.f), (float)(Hn - 1));
    const float x0f = floorf(xf), y0f = floorf(yf);
    wx = xf - x0f; wy = yf - y0f;
    const int x0 = (int)x0f, y0 = (int)y0f;
    const int x1 = min(x0 + 1, Wn - 1), y1 = min(y0 + 1, Hn - 1);
    i00 = y0 * Wn + x0; i01 = y0 * Wn + x1;
    i10 = y1 * Wn + x0; i11 = y1 * Wn + x1;
}

__device__ __forceinline__ float bilin(const float* __restrict__ base,
                                       int i00, int i01, int i10, int i11,
                                       float wx, float wy) {
    const float v00 = base[i00], v01 = base[i01];
    const float v10 = base[i10], v11 = base[i11];
    const float top = fmaf(wx, v01 - v00, v00);
    const float bot = fmaf(wx, v11 - v10, v10);
    return fmaf(wy, bot - top, top);
}

__global__ __launch_bounds__(256) void warp_loss_kernel(
        const float* __restrict__ L, const float* __restrict__ R,
        const float* __restrict__ Flm, const float* __restrict__ Frm,
        const float* __restrict__ G, double* __restrict__ accum) {
    // XCD k (= bid%8, round-robin dispatch) owns batch image k.
    // Per iteration an XCD's 360 blocks sweep a contiguous 72-row band:
    // chunk A in the first 36 rows, chunk B 36 rows below -> L2-resident.
    const int b     = blockIdx.x & 7;
    const int inner = blockIdx.x >> 3;

    const float* __restrict__ Lb = L + (size_t)b * Cn * HW;
    const float* __restrict__ Rb = R + (size_t)b * Cn * HW;
    const float* __restrict__ Gb = G + (size_t)b * Cn * HW;
    const float* __restrict__ fl = Flm + (size_t)b * 2 * HW;  // [0,HW)=x, [HW,2HW)=y
    const float* __restrict__ fr = Frm + (size_t)b * 2 * HW;

    float local = 0.f;

    // software pipeline: flows for iteration 0 (both chunks) loaded up front
    int pA = inner * BLK + (int)threadIdx.x;
    int pB = pA + NBX * BLK;
    float lfxA = fl[pA], lfyA = fl[HW + pA], rfxA = fr[pA], rfyA = fr[HW + pA];
    float lfxB = fl[pB], lfyB = fl[HW + pB], rfxB = fr[pB], rfyB = fr[HW + pB];

    for (int it = 0; it < ITER2; ++it) {
        // prefetch next iteration's flows (clamped; dummy on last iter)
        const int pAn = min((2 * (it + 1)) * NBX * BLK + inner * BLK + (int)threadIdx.x, HW - 1);
        const int pBn = min(pAn + NBX * BLK, HW - 1);
        const float nlfxA = fl[pAn], nlfyA = fl[HW + pAn];
        const float nrfxA = fr[pAn], nrfyA = fr[HW + pAn];
        const float nlfxB = fl[pBn], nlfyB = fl[HW + pBn];
        const float nrfxB = fr[pBn], nrfyB = fr[HW + pBn];

        const int yA = pA / Wn, xA = pA - yA * Wn;
        const int yB = pB / Wn, xB = pB - yB * Wn;

        int   la0, la1, la2, la3, ra0, ra1, ra2, ra3;
        int   lb0, lb1, lb2, lb3, rb0, rb1, rb2, rb3;
        float lwxA, lwyA, rwxA, rwyA, lwxB, lwyB, rwxB, rwyB;
        mk_coords((float)xA + lfxA, (float)yA + lfyA, la0, la1, la2, la3, lwxA, lwyA);
        mk_coords((float)xA + rfxA, (float)yA + rfyA, ra0, ra1, ra2, ra3, rwxA, rwyA);
        mk_coords((float)xB + lfxB, (float)yB + lfyB, lb0, lb1, lb2, lb3, lwxB, lwyB);
        mk_coords((float)xB + rfxB, (float)yB + rfyB, rb0, rb1, rb2, rb3, rwxB, rwyB);

        #pragma unroll
        for (int c = 0; c < Cn; ++c) {
            const float* __restrict__ Lc = Lb + c * HW;
            const float* __restrict__ Rc = Rb + c * HW;
            const float gA = Gb[c * HW + pA];
            const float gB = Gb[c * HW + pB];
            const float sLA = bilin(Lc, la0, la1, la2, la3, lwxA, lwyA);
            const float sRA = bilin(Rc, ra0, ra1, ra2, ra3, rwxA, rwyA);
            const float sLB = bilin(Lc, lb0, lb1, lb2, lb3, lwxB, lwyB);
            const float sRB = bilin(Rc, rb0, rb1, rb2, rb3, rwxB, rwyB);
            local += fabsf(sLA - gA) + fabsf(sRA - gA);
            local += fabsf(sLB - gB) + fabsf(sRB - gB);
        }

        lfxA = nlfxA; lfyA = nlfyA; rfxA = nrfxA; rfyA = nrfyA;
        lfxB = nlfxB; lfyB = nlfyB; rfxB = nrfxB; rfyB = nrfyB;
        pA = pAn; pB = pBn;
    }

    // wave(64) shuffle reduce -> LDS cross-wave -> one f64 atomic per block
    #pragma unroll
    for (int off = 32; off > 0; off >>= 1)
        local += __shfl_down(local, off, 64);

    __shared__ float wsum[4];
    const int lane = threadIdx.x & 63;
    const int wid  = threadIdx.x >> 6;
    if (lane == 0) wsum[wid] = local;
    __syncthreads();
    if (threadIdx.x == 0) {
        const float s = wsum[0] + wsum[1] + wsum[2] + wsum[3];
        atomicAdd(accum, (double)s);
    }
}

__global__ void finalize_kernel(const double* __restrict__ accum,
                                float* __restrict__ out) {
    out[0] = (float)(accum[0] / (double)NTOT);
}

extern "C" void kernel_launch(void* const* d_in, const int* in_sizes, int n_in,
                              void* d_out, int out_size, void* d_ws, size_t ws_size,
                              hipStream_t stream) {
    const float* L   = (const float*)d_in[0];
    const float* R   = (const float*)d_in[1];
    const float* flm = (const float*)d_in[2];
    const float* frm = (const float*)d_in[3];
    const float* gt  = (const float*)d_in[4];
    double* accum = (double*)d_ws;

    (void)hipMemsetAsync(accum, 0, sizeof(double), stream);
    warp_loss_kernel<<<NWG, BLK, 0, stream>>>(L, R, flm, frm, gt, accum);
    finalize_kernel<<<1, 1, 0, stream>>>(accum, (float*)d_out);
}

// Round 6
// 164.427 us; speedup vs baseline: 1.3510x; 1.3510x over previous
//
#include <hip/hip_runtime.h>

constexpr int Bn = 8, Cn = 3, Hn = 720, Wn = 1280;
constexpr int HW = Hn * Wn;                    // 921600 px per image
constexpr long long NTOT = (long long)Bn * Cn * HW;

constexpr int BLK  = 256;
constexpr int NBX  = 360;                      // blocks per XCD (= per batch)
constexpr int NWG  = 8 * NBX;                  // 2880 blocks
constexpr int ITER = HW / (NBX * BLK);         // 10 iterations, exact

// 8B tap-pair; 4B-aligned (gfx950 handles dword-aligned dwordx2)
typedef float f2 __attribute__((ext_vector_type(2), aligned(4)));

// One gather address per row: o0 -> (y0, x0), o1 -> (y1, x0).
// x0 = min(floor(xc), W-2) keeps the 8B pair in-row; wx in [0,1] (wx=1 at border).
__device__ __forceinline__ void mk2(float xf, float yf,
                                    int& o0, int& o1, float& wx, float& wy) {
    xf = fminf(fmaxf(xf, 0.f), (float)(Wn - 1));
    yf = fminf(fmaxf(yf, 0.f), (float)(Hn - 1));
    const int x0 = min((int)floorf(xf), Wn - 2);
    wx = xf - (float)x0;
    const float y0f = floorf(yf);
    const int y0 = (int)y0f;
    const int y1 = min(y0 + 1, Hn - 1);
    wy = yf - y0f;
    o0 = y0 * Wn + x0;
    o1 = y1 * Wn + x0;
}

__device__ __forceinline__ float bilin2(const float* __restrict__ base,
                                        int o0, int o1, float wx, float wy) {
    const f2 t = *reinterpret_cast<const f2*>(base + o0);
    const f2 b = *reinterpret_cast<const f2*>(base + o1);
    const float top = fmaf(wx, t[1] - t[0], t[0]);
    const float bot = fmaf(wx, b[1] - b[0], b[0]);
    return fmaf(wy, bot - top, top);
}

__global__ __launch_bounds__(256) void warp_loss_kernel(
        const float* __restrict__ L, const float* __restrict__ R,
        const float* __restrict__ Flm, const float* __restrict__ Frm,
        const float* __restrict__ G, double* __restrict__ accum) {
    // XCD k (= bid%8) owns batch image k; it-major band sweep keeps the
    // 72-row vertical tap overlap in that XCD's L2.
    const int b     = blockIdx.x & 7;
    const int inner = blockIdx.x >> 3;

    const float* __restrict__ Lb = L + (size_t)b * Cn * HW;
    const float* __restrict__ Rb = R + (size_t)b * Cn * HW;
    const float* __restrict__ Gb = G + (size_t)b * Cn * HW;
    const float* __restrict__ fl = Flm + (size_t)b * 2 * HW;  // [0,HW)=x, [HW,2HW)=y
    const float* __restrict__ fr = Frm + (size_t)b * 2 * HW;

    float local = 0.f;

    // software pipeline: flow for iteration 0 loaded up front
    int p = inner * BLK + (int)threadIdx.x;
    float lfx = fl[p], lfy = fl[HW + p];
    float rfx = fr[p], rfy = fr[HW + p];

    for (int it = 0; it < ITER; ++it) {
        const int p_next = min(((it + 1) * NBX + inner) * BLK + (int)threadIdx.x, HW - 1);
        const float nlfx = fl[p_next], nlfy = fl[HW + p_next];
        const float nrfx = fr[p_next], nrfy = fr[HW + p_next];

        const int y = p / Wn;
        const int x = p - y * Wn;

        int   lo0, lo1, ro0, ro1;
        float lwx, lwy, rwx, rwy;
        mk2((float)x + lfx, (float)y + lfy, lo0, lo1, lwx, lwy);
        mk2((float)x + rfx, (float)y + rfy, ro0, ro1, rwx, rwy);

        #pragma unroll
        for (int c = 0; c < Cn; ++c) {
            const float g  = Gb[c * HW + p];
            const float sL = bilin2(Lb + c * HW, lo0, lo1, lwx, lwy);
            const float sR = bilin2(Rb + c * HW, ro0, ro1, rwx, rwy);
            local += fabsf(sL - g) + fabsf(sR - g);
        }

        lfx = nlfx; lfy = nlfy; rfx = nrfx; rfy = nrfy;
        p = p_next;
    }

    // wave(64) shuffle reduce -> LDS cross-wave -> one f64 atomic per block
    #pragma unroll
    for (int off = 32; off > 0; off >>= 1)
        local += __shfl_down(local, off, 64);

    __shared__ float wsum[4];
    const int lane = threadIdx.x & 63;
    const int wid  = threadIdx.x >> 6;
    if (lane == 0) wsum[wid] = local;
    __syncthreads();
    if (threadIdx.x == 0) {
        const float s = wsum[0] + wsum[1] + wsum[2] + wsum[3];
        atomicAdd(accum, (double)s);
    }
}

__global__ void finalize_kernel(const double* __restrict__ accum,
                                float* __restrict__ out) {
    out[0] = (float)(accum[0] / (double)NTOT);
}

extern "C" void kernel_launch(void* const* d_in, const int* in_sizes, int n_in,
                              void* d_out, int out_size, void* d_ws, size_t ws_size,
                              hipStream_t stream) {
    const float* L   = (const float*)d_in[0];
    const float* R   = (const float*)d_in[1];
    const float* flm = (const float*)d_in[2];
    const float* frm = (const float*)d_in[3];
    const float* gt  = (const float*)d_in[4];
    double* accum = (double*)d_ws;

    (void)hipMemsetAsync(accum, 0, sizeof(double), stream);
    warp_loss_kernel<<<NWG, BLK, 0, stream>>>(L, R, flm, frm, gt, accum);
    finalize_kernel<<<1, 1, 0, stream>>>(accum, (float*)d_out);
}

// Round 7
// 138.138 us; speedup vs baseline: 1.6081x; 1.1903x over previous
//
#include <hip/hip_runtime.h>

constexpr int Bn = 8, Cn = 3, Hn = 720, Wn = 1280;
constexpr int HW = Hn * Wn;                    // 921600 px per image
constexpr long long NTOT = (long long)Bn * Cn * HW;

constexpr int BLK    = 256;
constexpr int NBX    = 256;                    // blocks per XCD (= per batch image)
constexpr int NWG    = 8 * NBX;                // 2048 blocks = 8/CU exactly
constexpr int CH     = NBX * BLK;              // 65536 px per chunk per image
constexpr int NCHUNK = (HW + CH - 1) / CH;     // 15 (14 full + 4096-px partial)

// 8B tap-pair; 4B-aligned (gfx950 handles dword-aligned dwordx2)
typedef float f2 __attribute__((ext_vector_type(2), aligned(4)));

// One gather address per row: o0 -> (y0, x0), o1 -> (y1, x0).
// x0 = min(floor(xc), W-2) keeps the 8B pair in-row; wx in [0,1] (wx=1 at border).
__device__ __forceinline__ void mk2(float xf, float yf,
                                    int& o0, int& o1, float& wx, float& wy) {
    xf = fminf(fmaxf(xf, 0.f), (float)(Wn - 1));
    yf = fminf(fmaxf(yf, 0.f), (float)(Hn - 1));
    const int x0 = min((int)floorf(xf), Wn - 2);
    wx = xf - (float)x0;
    const float y0f = floorf(yf);
    const int y0 = (int)y0f;
    const int y1 = min(y0 + 1, Hn - 1);
    wy = yf - y0f;
    o0 = y0 * Wn + x0;
    o1 = y1 * Wn + x0;
}

__device__ __forceinline__ float bilin2(const float* __restrict__ base,
                                        int o0, int o1, float wx, float wy) {
    const f2 t = *reinterpret_cast<const f2*>(base + o0);
    const f2 b = *reinterpret_cast<const f2*>(base + o1);
    const float top = fmaf(wx, t[1] - t[0], t[0]);
    const float bot = fmaf(wx, b[1] - b[0], b[0]);
    return fmaf(wy, bot - top, top);
}

__global__ __launch_bounds__(256) void warp_loss_kernel(
        const float* __restrict__ L, const float* __restrict__ R,
        const float* __restrict__ Flm, const float* __restrict__ Frm,
        const float* __restrict__ G, double* __restrict__ accum) {
    // XCD k (= bid%8) owns batch image k; its 256 blocks exactly fill the
    // XCD's 256 block-slots (32 CU x 8). Chunk-major sweep: per chunk the
    // XCD touches a ~51-row band (~3.4 MB incl. L,R,gt,flow) -> fits 4MB L2.
    const int b     = blockIdx.x & 7;
    const int inner = blockIdx.x >> 3;

    const float* __restrict__ Lb = L + (size_t)b * Cn * HW;
    const float* __restrict__ Rb = R + (size_t)b * Cn * HW;
    const float* __restrict__ Gb = G + (size_t)b * Cn * HW;
    const float* __restrict__ fl = Flm + (size_t)b * 2 * HW;  // [0,HW)=x, [HW,2HW)=y
    const float* __restrict__ fr = Frm + (size_t)b * 2 * HW;

    float local = 0.f;

    const int p0 = inner * BLK + (int)threadIdx.x;   // [0, 65536)
    // software pipeline: flow for chunk 0 loaded up front (p0 < HW always)
    float lfx = fl[p0], lfy = fl[HW + p0];
    float rfx = fr[p0], rfy = fr[HW + p0];

    for (int chunk = 0; chunk < NCHUNK; ++chunk) {
        const int p      = p0 + chunk * CH;              // may exceed HW on last chunk
        const int p_nxt  = min(p0 + (chunk + 1) * CH, HW - 1);  // clamped prefetch addr
        const float nlfx = fl[p_nxt], nlfy = fl[HW + p_nxt];
        const float nrfx = fr[p_nxt], nrfy = fr[HW + p_nxt];

        if (p < HW) {   // wave-uniform (p0 wave-contiguous, CH multiple of 64)
            const int y = p / Wn;
            const int x = p - y * Wn;

            int   lo0, lo1, ro0, ro1;
            float lwx, lwy, rwx, rwy;
            mk2((float)x + lfx, (float)y + lfy, lo0, lo1, lwx, lwy);
            mk2((float)x + rfx, (float)y + rfy, ro0, ro1, rwx, rwy);

            #pragma unroll
            for (int c = 0; c < Cn; ++c) {
                const float g  = Gb[c * HW + p];
                const float sL = bilin2(Lb + c * HW, lo0, lo1, lwx, lwy);
                const float sR = bilin2(Rb + c * HW, ro0, ro1, rwx, rwy);
                local += fabsf(sL - g) + fabsf(sR - g);
            }
        }

        lfx = nlfx; lfy = nlfy; rfx = nrfx; rfy = nrfy;
    }

    // wave(64) shuffle reduce -> LDS cross-wave -> one f64 atomic per block
    #pragma unroll
    for (int off = 32; off > 0; off >>= 1)
        local += __shfl_down(local, off, 64);

    __shared__ float wsum[4];
    const int lane = threadIdx.x & 63;
    const int wid  = threadIdx.x >> 6;
    if (lane == 0) wsum[wid] = local;
    __syncthreads();
    if (threadIdx.x == 0) {
        const float s = wsum[0] + wsum[1] + wsum[2] + wsum[3];
        atomicAdd(accum, (double)s);
    }
}

__global__ void finalize_kernel(const double* __restrict__ accum,
                                float* __restrict__ out) {
    out[0] = (float)(accum[0] / (double)NTOT);
}

extern "C" void kernel_launch(void* const* d_in, const int* in_sizes, int n_in,
                              void* d_out, int out_size, void* d_ws, size_t ws_size,
                              hipStream_t stream) {
    const float* L   = (const float*)d_in[0];
    const float* R   = (const float*)d_in[1];
    const float* flm = (const float*)d_in[2];
    const float* frm = (const float*)d_in[3];
    const float* gt  = (const float*)d_in[4];
    double* accum = (double*)d_ws;

    (void)hipMemsetAsync(accum, 0, sizeof(double), stream);
    warp_loss_kernel<<<NWG, BLK, 0, stream>>>(L, R, flm, frm, gt, accum);
    finalize_kernel<<<1, 1, 0, stream>>>(accum, (float*)d_out);
}

// Round 8
// 138.116 us; speedup vs baseline: 1.6083x; 1.0002x over previous
//
#include <hip/hip_runtime.h>

constexpr int Bn = 8, Cn = 3, Hn = 720, Wn = 1280;
constexpr int HW = Hn * Wn;                    // 921600 px per image
constexpr long long NTOT = (long long)Bn * Cn * HW;

constexpr int BLK    = 256;
constexpr int NBX    = 512;                    // blocks per XCD (= per batch image)
constexpr int NWG    = 8 * NBX;                // 4096 blocks = 16/CU (2 exact rounds of 8)
constexpr int CH     = NBX * BLK;              // 131072 px per chunk per image
constexpr int NCHUNK = (HW + CH - 1) / CH;     // 8 (7 full + 4096-px partial)

// 8B tap-pair; 4B-aligned (gfx950 handles dword-aligned dwordx2)
typedef float f2 __attribute__((ext_vector_type(2), aligned(4)));

// One gather address per row: o0 -> (y0, x0), o1 -> (y1, x0).
// x0 = min(floor(xc), W-2) keeps the 8B pair in-row; wx in [0,1] (wx=1 at border).
__device__ __forceinline__ void mk2(float xf, float yf,
                                    int& o0, int& o1, float& wx, float& wy) {
    xf = fminf(fmaxf(xf, 0.f), (float)(Wn - 1));
    yf = fminf(fmaxf(yf, 0.f), (float)(Hn - 1));
    const int x0 = min((int)floorf(xf), Wn - 2);
    wx = xf - (float)x0;
    const float y0f = floorf(yf);
    const int y0 = (int)y0f;
    const int y1 = min(y0 + 1, Hn - 1);
    wy = yf - y0f;
    o0 = y0 * Wn + x0;
    o1 = y1 * Wn + x0;
}

__device__ __forceinline__ float bilin2(const float* __restrict__ base,
                                        int o0, int o1, float wx, float wy) {
    const f2 t = *reinterpret_cast<const f2*>(base + o0);
    const f2 b = *reinterpret_cast<const f2*>(base + o1);
    const float top = fmaf(wx, t[1] - t[0], t[0]);
    const float bot = fmaf(wx, b[1] - b[0], b[0]);
    return fmaf(wy, bot - top, top);
}

__global__ __launch_bounds__(256) void warp_loss_kernel(
        const float* __restrict__ L, const float* __restrict__ R,
        const float* __restrict__ Flm, const float* __restrict__ Frm,
        const float* __restrict__ G, double* __restrict__ accum) {
    // XCD k (= bid%8) owns batch image k. 512 blocks/XCD = 2 exact rounds of
    // the XCD's 256 block-slots: 8 co-resident + 8 queued per CU, so the HW
    // scheduler backfills finish-time skew instead of idling slots (R7's 63%).
    const int b     = blockIdx.x & 7;
    const int inner = blockIdx.x >> 3;

    const float* __restrict__ Lb = L + (size_t)b * Cn * HW;
    const float* __restrict__ Rb = R + (size_t)b * Cn * HW;
    const float* __restrict__ Gb = G + (size_t)b * Cn * HW;
    const float* __restrict__ fl = Flm + (size_t)b * 2 * HW;  // [0,HW)=x, [HW,2HW)=y
    const float* __restrict__ fr = Frm + (size_t)b * 2 * HW;

    float local = 0.f;

    const int p0 = inner * BLK + (int)threadIdx.x;   // [0, 131072)
    // software pipeline: flow for chunk 0 loaded up front (p0 < HW always)
    float lfx = fl[p0], lfy = fl[HW + p0];
    float rfx = fr[p0], rfy = fr[HW + p0];

    for (int chunk = 0; chunk < NCHUNK; ++chunk) {
        const int p      = p0 + chunk * CH;              // may exceed HW on last chunk
        const int p_nxt  = min(p0 + (chunk + 1) * CH, HW - 1);  // clamped prefetch addr
        const float nlfx = fl[p_nxt], nlfy = fl[HW + p_nxt];
        const float nrfx = fr[p_nxt], nrfy = fr[HW + p_nxt];

        if (p < HW) {   // wave-uniform (p0 wave-contiguous, CH multiple of 64)
            const int y = p / Wn;
            const int x = p - y * Wn;

            int   lo0, lo1, ro0, ro1;
            float lwx, lwy, rwx, rwy;
            mk2((float)x + lfx, (float)y + lfy, lo0, lo1, lwx, lwy);
            mk2((float)x + rfx, (float)y + rfy, ro0, ro1, rwx, rwy);

            #pragma unroll
            for (int c = 0; c < Cn; ++c) {
                const float g  = Gb[c * HW + p];
                const float sL = bilin2(Lb + c * HW, lo0, lo1, lwx, lwy);
                const float sR = bilin2(Rb + c * HW, ro0, ro1, rwx, rwy);
                local += fabsf(sL - g) + fabsf(sR - g);
            }
        }

        lfx = nlfx; lfy = nlfy; rfx = nrfx; rfy = nrfy;
    }

    // wave(64) shuffle reduce -> LDS cross-wave -> one f64 atomic per block
    #pragma unroll
    for (int off = 32; off > 0; off >>= 1)
        local += __shfl_down(local, off, 64);

    __shared__ float wsum[4];
    const int lane = threadIdx.x & 63;
    const int wid  = threadIdx.x >> 6;
    if (lane == 0) wsum[wid] = local;
    __syncthreads();
    if (threadIdx.x == 0) {
        const float s = wsum[0] + wsum[1] + wsum[2] + wsum[3];
        atomicAdd(accum, (double)s);
    }
}

__global__ void finalize_kernel(const double* __restrict__ accum,
                                float* __restrict__ out) {
    out[0] = (float)(accum[0] / (double)NTOT);
}

extern "C" void kernel_launch(void* const* d_in, const int* in_sizes, int n_in,
                              void* d_out, int out_size, void* d_ws, size_t ws_size,
                              hipStream_t stream) {
    const float* L   = (const float*)d_in[0];
    const float* R   = (const float*)d_in[1];
    const float* flm = (const float*)d_in[2];
    const float* frm = (const float*)d_in[3];
    const float* gt  = (const float*)d_in[4];
    double* accum = (double*)d_ws;

    (void)hipMemsetAsync(accum, 0, sizeof(double), stream);
    warp_loss_kernel<<<NWG, BLK, 0, stream>>>(L, R, flm, frm, gt, accum);
    finalize_kernel<<<1, 1, 0, stream>>>(accum, (float*)d_out);
}